// Round 1
// baseline (953.299 us; speedup 1.0000x reference)
//
#include <hip/hip_runtime.h>

#define NN 2048
#define PSTR 72  // bf16 LDS row stride (64 + 8 pad -> 2-way-free bank pattern)

typedef __attribute__((ext_vector_type(8))) short short8;
typedef __attribute__((ext_vector_type(4))) float floatx4;

__device__ __forceinline__ unsigned short f2bf(float f){
  unsigned u = __float_as_uint(f);
  u += 0x7fffu + ((u >> 16) & 1u);
  return (unsigned short)(u >> 16);
}
__device__ __forceinline__ float sigm(float x){ return 1.f/(1.f+__expf(-x)); }

// ---- init: hidden = h0 broadcast, cell = actors[:,0,:] ----
__global__ __launch_bounds__(256) void init_kernel(const float* __restrict__ actors,
    const float* __restrict__ h0, float* __restrict__ hidden, float* __restrict__ cell){
  int idx = blockIdx.x*256 + threadIdx.x;
  int n = idx >> 7, c = idx & 127;
  hidden[idx] = h0[c];
  cell[idx]   = actors[(size_t)n*2560 + c];
}

// ---- bitmasks for the 4 used adjacency slices ----
__global__ __launch_bounds__(256) void mask_kernel(const int* __restrict__ adj,
    unsigned long long* __restrict__ bm){
  const int E[4] = {0,4,9,14};
  int t = blockIdx.y;
  int wv = threadIdx.x >> 6, lane = threadIdx.x & 63;
  int n = blockIdx.x*4 + wv;
  const int* row = adj + (size_t)n*40960 + (size_t)E[t]*2048;
  unsigned long long* outp = bm + ((size_t)t*2048 + n)*32;
  for (int it=0; it<32; ++it){
    unsigned long long bal = __ballot(row[it*64 + lane] > 0);
    if (lane == 0) outp[it] = bal;
  }
}

// ---- Wh = [X|hidden] @ Wg[g]; writes WhT (bf16, [g][o][n]) + s_src/s_dst fp32 ----
__global__ __launch_bounds__(256) void wh_kernel(const float* __restrict__ actors,
    const float* __restrict__ hidden, const float* __restrict__ Wg, const float* __restrict__ ag,
    unsigned short* __restrict__ WhT, float* __restrict__ s_src, float* __restrict__ s_dst, int xoff){
  __shared__ float gin[32*260];
  __shared__ float red[32*8*2];
  int g = blockIdx.y, n0 = blockIdx.x*32, tid = threadIdx.x;
  for (int idx = tid; idx < 8192; idx += 256){
    int r = idx >> 8, c = idx & 255;
    float v = (c < 128) ? actors[(size_t)(n0+r)*2560 + xoff + c]
                        : hidden[(size_t)(n0+r)*128 + (c-128)];
    gin[r*260 + c] = v;
  }
  __syncthreads();
  int r = tid >> 3, cg = tid & 7, c0 = cg*16;
  float acc[16];
  #pragma unroll
  for (int j=0;j<16;++j) acc[j] = 0.f;
  const float* wg = Wg + (size_t)g*32768 + c0;
  for (int f=0; f<256; ++f){
    float gv = gin[r*260 + f];
    const floatx4* w4 = (const floatx4*)(wg + (size_t)f*128);
    floatx4 w0 = w4[0], w1 = w4[1], w2 = w4[2], w3 = w4[3];
    #pragma unroll
    for (int j=0;j<4;++j){
      acc[j]    += gv*w0[j]; acc[4+j]  += gv*w1[j];
      acc[8+j]  += gv*w2[j]; acc[12+j] += gv*w3[j];
    }
  }
  const float* agp = ag + g*256 + c0;
  float sp = 0.f, dp = 0.f;
  #pragma unroll
  for (int j=0;j<16;++j){ sp += acc[j]*agp[j]; dp += acc[j]*agp[128+j]; }
  red[(r*8+cg)*2]   = sp;
  red[(r*8+cg)*2+1] = dp;
  unsigned short* wt = WhT + (size_t)g*262144 + (size_t)c0*2048 + (n0+r);
  #pragma unroll
  for (int j=0;j<16;++j) wt[(size_t)j*2048] = f2bf(acc[j]);
  __syncthreads();
  if (tid < 32){
    float a = 0.f, d = 0.f;
    #pragma unroll
    for (int k=0;k<8;++k){ a += red[(tid*8+k)*2]; d += red[(tid*8+k)*2+1]; }
    s_src[g*2048 + n0 + tid] = a;
    s_dst[g*2048 + n0 + tid] = d;
  }
}

// ---- fused masked-softmax + PV (bf16 MFMA) + elu -> g buffer ----
__global__ __launch_bounds__(256) void attn_kernel(const unsigned long long* __restrict__ bm,
    const unsigned short* __restrict__ WhT, const float* __restrict__ s_src,
    const float* __restrict__ s_dst, float* __restrict__ gout, int t){
  __shared__ __align__(16) unsigned short whs[128*PSTR];
  __shared__ __align__(16) unsigned short Ps[32*PSTR];
  __shared__ float zbuf[256];
  __shared__ float zrow[32];
  int g = blockIdx.y, n0 = blockIdx.x*32, tid = threadIdx.x;
  int pr = tid >> 3, pseg = tid & 7;
  int wv = tid >> 6, lane = tid & 63, quad = lane >> 4, l16 = lane & 15;
  float srcv = s_src[g*2048 + n0 + pr];
  const unsigned long long* mrow = bm + ((size_t)t*2048 + n0 + pr)*32;
  const float* sd = s_dst + g*2048;
  const unsigned short* whg = WhT + (size_t)g*262144;
  int sc = tid >> 1, sh = tid & 1;
  const unsigned short* stg = whg + (size_t)sc*2048 + sh*32;
  float z_acc = 0.f;
  floatx4 acc00 = {0.f,0.f,0.f,0.f};
  floatx4 acc01 = acc00, acc10 = acc00, acc11 = acc00;
  for (int tile=0; tile<32; ++tile){
    int m0 = tile*64;
    __syncthreads();
    { // stage Wh^T tile (128 cols x 64 m, bf16)
      const uint4* s4 = (const uint4*)(stg + m0);
      uint4 v0 = s4[0], v1 = s4[1], v2 = s4[2], v3 = s4[3];
      uint4* d4 = (uint4*)&whs[sc*PSTR + sh*32];
      d4[0]=v0; d4[1]=v1; d4[2]=v2; d4[3]=v3;
    }
    { // generate P tile (32 rows x 64 m)
      unsigned mb = (unsigned)(mrow[tile] >> (pseg*8)) & 0xffu;
      const floatx4* sd4 = (const floatx4*)(sd + m0 + pseg*8);
      floatx4 sa = sd4[0], sb = sd4[1];
      float sv[8] = {sa[0],sa[1],sa[2],sa[3],sb[0],sb[1],sb[2],sb[3]};
      unsigned short us[8];
      #pragma unroll
      for (int j=0;j<8;++j){
        float s = srcv + sv[j];
        s = s > 0.f ? s : 0.2f*s;            // leaky_relu
        float p = ((mb >> j) & 1u) ? __expf(s) : 0.f;
        z_acc += p;
        us[j] = f2bf(p);
      }
      uint4 pk;
      pk.x = us[0] | ((unsigned)us[1] << 16);
      pk.y = us[2] | ((unsigned)us[3] << 16);
      pk.z = us[4] | ((unsigned)us[5] << 16);
      pk.w = us[6] | ((unsigned)us[7] << 16);
      *(uint4*)&Ps[pr*PSTR + pseg*8] = pk;
    }
    __syncthreads();
    #pragma unroll
    for (int kh=0; kh<2; ++kh){
      int kc = kh*32 + (quad << 3);
      short8 a0 = *(const short8*)&Ps[l16*PSTR + kc];
      short8 a1 = *(const short8*)&Ps[(16+l16)*PSTR + kc];
      short8 b0 = *(const short8*)&whs[(wv*32 + l16)*PSTR + kc];
      short8 b1 = *(const short8*)&whs[(wv*32 + 16 + l16)*PSTR + kc];
      acc00 = __builtin_amdgcn_mfma_f32_16x16x32_bf16(a0, b0, acc00, 0, 0, 0);
      acc01 = __builtin_amdgcn_mfma_f32_16x16x32_bf16(a0, b1, acc01, 0, 0, 0);
      acc10 = __builtin_amdgcn_mfma_f32_16x16x32_bf16(a1, b0, acc10, 0, 0, 0);
      acc11 = __builtin_amdgcn_mfma_f32_16x16x32_bf16(a1, b1, acc11, 0, 0, 0);
    }
  }
  zbuf[tid] = z_acc;   // zbuf[pr*8+pseg]
  __syncthreads();
  if (tid < 32){
    float s = 0.f;
    #pragma unroll
    for (int k=0;k<8;++k) s += zbuf[tid*8+k];
    zrow[tid] = s;
  }
  __syncthreads();
  float* go = gout + (size_t)g*262144;
  #pragma unroll
  for (int i=0;i<2;++i){
    floatx4 a_0 = i ? acc10 : acc00;
    floatx4 a_1 = i ? acc11 : acc01;
    #pragma unroll
    for (int ii=0; ii<4; ++ii){
      int row = i*16 + quad*4 + ii;          // verified C/D layout: col=lane&15, row=quad*4+reg
      float inv = 1.f / zrow[row];
      float v0 = a_0[ii]*inv; v0 = v0 > 0.f ? v0 : __expf(v0) - 1.f;  // elu
      float v1 = a_1[ii]*inv; v1 = v1 > 0.f ? v1 : __expf(v1) - 1.f;
      go[(size_t)(n0+row)*128 + wv*32 + l16]      = v0;
      go[(size_t)(n0+row)*128 + wv*32 + 16 + l16] = v1;
    }
  }
}

// ---- LSTM gate combine + hidden@W out-projection ----
__global__ __launch_bounds__(256) void gate_kernel(const float* __restrict__ gbuf,
    float* __restrict__ cell, float* __restrict__ hidden, const float* __restrict__ W,
    const float* __restrict__ b, float* __restrict__ y, int t){
  __shared__ float h[256];
  int tid = threadIdx.x;
  int r = tid >> 7, o = tid & 127;
  int n = blockIdx.x*2 + r;
  size_t idx = (size_t)n*128 + o;
  float g0 = gbuf[idx], g1 = gbuf[262144+idx], g2 = gbuf[524288+idx], g3 = gbuf[786432+idx];
  float fg = sigm(g0), ig = sigm(g1), ic = tanhf(g2), og = sigm(g3);
  float cl = cell[idx]*fg + ig*ic;
  float hd = tanhf(cl)*og;
  cell[idx] = cl; hidden[idx] = hd;
  h[tid] = hd;
  __syncthreads();
  float acc = b[o];
  const float* hr = h + r*128;
  for (int k=0;k<128;++k) acc += hr[k]*W[k*128+o];
  y[(size_t)n*512 + o*4 + t] = sigm(acc);
}

// ---- temporal conv layers ----
template<int TIN, bool LAST>
__global__ __launch_bounds__(256) void conv_kernel(const float* __restrict__ yin,
    const float* __restrict__ cw, const float* __restrict__ cb, float* __restrict__ yout, int l){
  __shared__ float ylds[2][128][4];
  int tid = threadIdx.x;
  int r = tid >> 7, o = tid & 127;
  int n = blockIdx.x*2 + r;
  float4 yv = *(const float4*)&yin[(size_t)n*512 + o*4];
  *(float4*)&ylds[r][o][0] = yv;
  __syncthreads();
  const float* w = cw + (size_t)l*32768 + o*256;
  float acc[TIN-1];
  #pragma unroll
  for (int j=0;j<TIN-1;++j) acc[j] = 0.f;
  for (int k=0;k<128;++k){
    float w0 = w[k*2], w1 = w[k*2+1];
    float y0 = ylds[r][k][0], y1 = ylds[r][k][1];
    acc[0] += y0*w0 + y1*w1;
    if (TIN > 2){
      float y2 = ylds[r][k][2];
      acc[1] += y1*w0 + y2*w1;
      if (TIN > 3){
        float y3 = ylds[r][k][3];
        acc[2] += y2*w0 + y3*w1;
      }
    }
  }
  float bb = cb[l*128 + o];
  if (LAST){
    yout[(size_t)n*128 + o] = acc[0] + bb;
  } else {
    #pragma unroll
    for (int tt=0; tt<TIN-1; ++tt) yout[(size_t)n*512 + o*4 + tt] = acc[tt] + bb;
  }
}

extern "C" void kernel_launch(void* const* d_in, const int* in_sizes, int n_in,
                              void* d_out, int out_size, void* d_ws, size_t ws_size,
                              hipStream_t stream) {
  const float* actors = (const float*)d_in[0];
  const int*   adj    = (const int*)d_in[1];
  const float* Wg     = (const float*)d_in[2];
  const float* ag     = (const float*)d_in[3];
  const float* W      = (const float*)d_in[4];
  const float* b      = (const float*)d_in[5];
  const float* h0     = (const float*)d_in[6];
  const float* cw     = (const float*)d_in[7];
  const float* cb     = (const float*)d_in[8];
  float* out = (float*)d_out;

  char* ws = (char*)d_ws;
  unsigned long long* bm = (unsigned long long*)ws;             // 2 MB
  float* hidden       = (float*)(ws + (size_t)(2u<<20));        // 1 MB
  float* cell         = (float*)(ws + (size_t)(3u<<20));        // 1 MB
  unsigned short* WhT = (unsigned short*)(ws + (size_t)(4u<<20)); // 2 MB bf16 [4][128][2048]
  float* s_src        = (float*)(ws + (size_t)(6u<<20));        // 32 KB
  float* s_dst        = (float*)(ws + (size_t)(6u<<20) + 32768);
  float* gbuf         = (float*)(ws + (size_t)(7u<<20));        // 4 MB [4][N][128]
  float* yA           = (float*)(ws + (size_t)(11u<<20));       // 4 MB [N][128][4]
  float* yB           = (float*)(ws + (size_t)(15u<<20));       // 4 MB

  const int XI[4] = {4, 9, 14, 19};

  init_kernel<<<1024, 256, 0, stream>>>(actors, h0, hidden, cell);
  mask_kernel<<<dim3(512,4), 256, 0, stream>>>(adj, bm);
  for (int t=0; t<4; ++t){
    wh_kernel  <<<dim3(64,4), 256, 0, stream>>>(actors, hidden, Wg, ag, WhT, s_src, s_dst, XI[t]*128);
    attn_kernel<<<dim3(64,4), 256, 0, stream>>>(bm, WhT, s_src, s_dst, gbuf, t);
    gate_kernel<<<1024, 256, 0, stream>>>(gbuf, cell, hidden, W, b, yA, t);
  }
  conv_kernel<4,false><<<1024, 256, 0, stream>>>(yA, cw, cb, yB, 0);
  conv_kernel<3,false><<<1024, 256, 0, stream>>>(yB, cw, cb, yA, 1);
  conv_kernel<2,true> <<<1024, 256, 0, stream>>>(yA, cw, cb, out, 2);
}

// Round 2
// 654.707 us; speedup vs baseline: 1.4561x; 1.4561x over previous
//
#include <hip/hip_runtime.h>

typedef __attribute__((ext_vector_type(8))) short short8;
typedef __attribute__((ext_vector_type(4))) float floatx4;

#define MFMA16(a,b,c) __builtin_amdgcn_mfma_f32_16x16x32_bf16(a,b,c,0,0,0)

__device__ __forceinline__ unsigned short f2bf(float f){
  unsigned u = __float_as_uint(f);
  u += 0x7fffu + ((u >> 16) & 1u);
  return (unsigned short)(u >> 16);
}
__device__ __forceinline__ float sigm(float x){ return 1.f/(1.f+__expf(-x)); }

// ---- init: hbf = h0 bf16 broadcast, cell = actors[:,0,:] ----
__global__ __launch_bounds__(256) void init_kernel(const float* __restrict__ actors,
    const float* __restrict__ h0, unsigned short* __restrict__ hbf, float* __restrict__ cell){
  int idx = blockIdx.x*256 + threadIdx.x;
  int n = idx >> 7, c = idx & 127;
  hbf[idx]  = f2bf(h0[c]);
  cell[idx] = actors[(size_t)n*2560 + c];
}

// ---- WgT[g][o][f] bf16 from Wg[g][f][o] fp32 ----
__global__ __launch_bounds__(256) void wgt_kernel(const float* __restrict__ Wg,
    unsigned short* __restrict__ WgT){
  int e = blockIdx.x*256 + threadIdx.x;            // 131072
  int g = e >> 15, o = (e >> 8) & 127, f = e & 255;
  WgT[(size_t)g*32768 + o*256 + f] = f2bf(Wg[(size_t)g*32768 + f*128 + o]);
}

// ---- cwT[l][k][tap][o] fp32 from conv_w[l][o][k][tap] (coalesced writes) ----
__global__ __launch_bounds__(256) void cwt_kernel(const float* __restrict__ cw,
    float* __restrict__ cwT){
  int e = blockIdx.x*256 + threadIdx.x;            // 49152
  int l = e >> 14, r = e & 16383, k = r >> 7, o = r & 127;
  cwT[(size_t)l*32768 + k*256 + o]       = cw[(size_t)l*32768 + o*256 + k*2];
  cwT[(size_t)l*32768 + k*256 + 128 + o] = cw[(size_t)l*32768 + o*256 + k*2 + 1];
}

// ---- bitmasks for the 4 used adjacency slices ----
__global__ __launch_bounds__(256) void mask_kernel(const int* __restrict__ adj,
    unsigned long long* __restrict__ bm){
  const int E[4] = {0,4,9,14};
  int t = blockIdx.y;
  int wv = threadIdx.x >> 6, lane = threadIdx.x & 63;
  int n = blockIdx.x*4 + wv;
  const int* row = adj + (size_t)n*40960 + (size_t)E[t]*2048;
  unsigned long long* outp = bm + ((size_t)t*2048 + n)*32;
  for (int it=0; it<32; ++it){
    unsigned long long bal = __ballot(row[it*64 + lane] > 0);
    if (lane == 0) outp[it] = bal;
  }
}

// ---- WhT[g][o][n] bf16 = (Wg^T @ [X|h]^T), MFMA K=256; s_src/s_dst from fp32 acc ----
__global__ __launch_bounds__(256) void whgemm_kernel(const float* __restrict__ actors,
    const unsigned short* __restrict__ hbf, const unsigned short* __restrict__ WgT,
    const float* __restrict__ ag, unsigned short* __restrict__ WhT,
    float* __restrict__ s_src, float* __restrict__ s_dst, int xoff){
  __shared__ __align__(16) unsigned short ginb[32*264];   // [n=32][k=256 +8 pad]
  __shared__ float sred[4][2][32];
  int g = blockIdx.y, n0 = blockIdx.x*32, tid = threadIdx.x;
  { // stage gin tile as bf16: row = tid>>3, k-chunk = (tid&7)*32
    int row = tid >> 3, q = tid & 7;
    if (q < 4){
      const float4* src = (const float4*)(actors + (size_t)(n0+row)*2560 + xoff + q*32);
      unsigned short* dst = &ginb[row*264 + q*32];
      #pragma unroll
      for (int j=0;j<4;++j){
        float4 a = src[2*j], b = src[2*j+1];
        unsigned short tmp[8] = {f2bf(a.x),f2bf(a.y),f2bf(a.z),f2bf(a.w),
                                 f2bf(b.x),f2bf(b.y),f2bf(b.z),f2bf(b.w)};
        *(uint4*)(dst + j*8) = *(const uint4*)tmp;
      }
    } else {
      const uint4* src = (const uint4*)(hbf + (size_t)(n0+row)*128 + (q-4)*32);
      uint4* dst = (uint4*)&ginb[row*264 + 128 + (q-4)*32];
      #pragma unroll
      for (int j=0;j<4;++j) dst[j] = src[j];
    }
  }
  __syncthreads();
  int wv = tid>>6, lane = tid&63, quad = lane>>4, l16 = lane&15;
  int ob = wv*32;
  floatx4 acc[2][2];
  #pragma unroll
  for (int i=0;i<2;++i) for (int j=0;j<2;++j) acc[i][j] = (floatx4){0.f,0.f,0.f,0.f};
  const unsigned short* wga = WgT + (size_t)g*32768;
  #pragma unroll
  for (int kh=0; kh<8; ++kh){
    int k = kh*32 + quad*8;
    short8 a0 = *(const short8*)(wga + (size_t)(ob + l16)*256 + k);
    short8 a1 = *(const short8*)(wga + (size_t)(ob + 16 + l16)*256 + k);
    #pragma unroll
    for (int j=0;j<2;++j){
      short8 b = *(const short8*)&ginb[(j*16 + l16)*264 + k];
      acc[0][j] = MFMA16(a0, b, acc[0][j]);
      acc[1][j] = MFMA16(a1, b, acc[1][j]);
    }
  }
  // epilogue: store WhT bf16 + fold ag dot-products (exact fp32 acc)
  float agS[2][4], agD[2][4];
  #pragma unroll
  for (int i=0;i<2;++i)
    #pragma unroll
    for (int r=0;r<4;++r){
      int o = ob + i*16 + quad*4 + r;
      agS[i][r] = ag[g*256 + o];
      agD[i][r] = ag[g*256 + 128 + o];
    }
  unsigned short* wht = WhT + (size_t)g*262144;
  float psrc[2], pdst[2];
  #pragma unroll
  for (int j=0;j<2;++j){
    float ps = 0.f, pd = 0.f;
    #pragma unroll
    for (int i=0;i<2;++i)
      #pragma unroll
      for (int r=0;r<4;++r){
        float v = acc[i][j][r];
        ps += v*agS[i][r]; pd += v*agD[i][r];
        wht[(size_t)(ob + i*16 + quad*4 + r)*2048 + n0 + j*16 + l16] = f2bf(v);
      }
    psrc[j] = ps; pdst[j] = pd;
  }
  #pragma unroll
  for (int j=0;j<2;++j){
    psrc[j] += __shfl_down(psrc[j], 16); psrc[j] += __shfl_down(psrc[j], 32);
    pdst[j] += __shfl_down(pdst[j], 16); pdst[j] += __shfl_down(pdst[j], 32);
  }
  if (quad == 0){
    #pragma unroll
    for (int j=0;j<2;++j){
      sred[wv][0][j*16+l16] = psrc[j];
      sred[wv][1][j*16+l16] = pdst[j];
    }
  }
  __syncthreads();
  if (tid < 64){
    int which = tid>>5, n = tid&31;
    float s = sred[0][which][n]+sred[1][which][n]+sred[2][which][n]+sred[3][which][n];
    (which ? s_dst : s_src)[g*2048 + n0 + n] = s;
  }
}

// ---- fused masked-softmax + PV: 512 thr = 4 K-groups x 2 o-waves, BK=64 ----
__global__ __launch_bounds__(512) void attn_kernel(const unsigned long long* __restrict__ bm,
    const unsigned short* __restrict__ WhT, const float* __restrict__ s_src,
    const float* __restrict__ s_dst, float* __restrict__ gout, int t){
  __shared__ __align__(16) char lds_raw[94336];
  int g = blockIdx.y, n0 = blockIdx.x*32, tid = threadIdx.x;
  int wv = tid>>6, lane = tid&63, quad = lane>>4, l16 = lane&15;
  int grp = tid>>7, gtid = tid&127, ow = wv&1;
  unsigned short* whs = (unsigned short*)(lds_raw + grp*18432);      // [o=128][m=64 +8]
  unsigned short* Ps  = (unsigned short*)(lds_raw + 73728 + grp*4608); // [n=32][m=64 +8]
  float* zpart = (float*)(lds_raw + 92160);
  float* zrow  = (float*)(lds_raw + 94208);
  float* obufA = (float*)(lds_raw);            // reuse whs region after main loop
  float* obufB = (float*)(lds_raw + 16896);

  const unsigned short* whg = WhT + (size_t)g*262144 + (size_t)gtid*2048;
  int prow = gtid>>2, pseg = gtid&3;
  float srcv = s_src[g*2048 + n0 + prow];
  const unsigned long long* mrow = bm + ((size_t)t*2048 + n0 + prow)*32;
  const float* sd = s_dst + g*2048;
  float z_acc = 0.f;
  floatx4 acc[2][4];
  #pragma unroll
  for (int i=0;i<2;++i) for (int j=0;j<4;++j) acc[i][j] = (floatx4){0.f,0.f,0.f,0.f};

  for (int c=0; c<8; ++c){
    int m0 = grp*512 + c*64;
    __syncthreads();
    { // stage Wh^T chunk: thread gtid = o-row, 64 m = 8 uint4
      const uint4* src = (const uint4*)(whg + m0);
      uint4 v[8];
      #pragma unroll
      for (int j=0;j<8;++j) v[j] = src[j];
      uint4* dst = (uint4*)(whs + gtid*72);
      #pragma unroll
      for (int j=0;j<8;++j) dst[j] = v[j];
    }
    { // generate P chunk: thread -> (row=gtid>>2, 16 m at pseg*16)
      unsigned long long mw = mrow[grp*8 + c];
      unsigned short mb = (unsigned short)(mw >> (pseg*16));
      const float4* sd4 = (const float4*)(sd + m0 + pseg*16);
      float4 s0 = sd4[0], s1 = sd4[1], s2 = sd4[2], s3 = sd4[3];
      float sv[16] = {s0.x,s0.y,s0.z,s0.w, s1.x,s1.y,s1.z,s1.w,
                      s2.x,s2.y,s2.z,s2.w, s3.x,s3.y,s3.z,s3.w};
      unsigned short us[16];
      #pragma unroll
      for (int j=0;j<16;++j){
        float s = srcv + sv[j];
        s = s > 0.f ? s : 0.2f*s;                 // leaky_relu
        float p = ((mb >> j) & 1) ? __expf(s) : 0.f;
        z_acc += p;
        us[j] = f2bf(p);
      }
      uint4* pd = (uint4*)(Ps + prow*72 + pseg*16);
      pd[0] = *(const uint4*)us;
      pd[1] = *(const uint4*)(us+8);
    }
    __syncthreads();
    #pragma unroll
    for (int kh=0; kh<2; ++kh){
      int kc = kh*32 + quad*8;
      short8 a0 = *(const short8*)(Ps + l16*72 + kc);
      short8 a1 = *(const short8*)(Ps + (16+l16)*72 + kc);
      #pragma unroll
      for (int j=0;j<4;++j){
        short8 b = *(const short8*)(whs + (size_t)(ow*64 + j*16 + l16)*72 + kc);
        acc[0][j] = MFMA16(a0, b, acc[0][j]);
        acc[1][j] = MFMA16(a1, b, acc[1][j]);
      }
    }
  }
  zpart[tid] = z_acc;
  __syncthreads();                 // last whs reads done; zpart visible after next barrier
  if (grp < 2){
    float* obx = (grp & 1) ? obufB : obufA;
    #pragma unroll
    for (int i=0;i<2;++i)
      #pragma unroll
      for (int j=0;j<4;++j)
        #pragma unroll
        for (int r=0;r<4;++r)
          obx[(i*16 + quad*4 + r)*132 + ow*64 + j*16 + l16] = acc[i][j][r];
  }
  __syncthreads();
  if (tid < 32){
    float s = 0.f;
    #pragma unroll
    for (int k=0;k<16;++k) s += zpart[(k>>2)*128 + tid*4 + (k&3)];
    zrow[tid] = s;
  }
  if (grp >= 2){
    float* obx = (grp & 1) ? obufB : obufA;
    #pragma unroll
    for (int i=0;i<2;++i)
      #pragma unroll
      for (int j=0;j<4;++j)
        #pragma unroll
        for (int r=0;r<4;++r)
          obx[(i*16 + quad*4 + r)*132 + ow*64 + j*16 + l16] += acc[i][j][r];
  }
  __syncthreads();
  { // epilogue: normalize + elu + store, 8 contiguous floats/thread
    int row = tid>>4, c0 = (tid&15)*8;
    float inv = 1.f / zrow[row];
    float* go = gout + (size_t)g*262144 + (size_t)(n0+row)*128 + c0;
    #pragma unroll
    for (int j=0;j<8;++j){
      float v = (obufA[row*132 + c0 + j] + obufB[row*132 + c0 + j]) * inv;
      go[j] = v > 0.f ? v : __expf(v) - 1.f;     // elu
    }
  }
}

// ---- LSTM gate combine + hidden@W out-projection ----
__global__ __launch_bounds__(256) void gate_kernel(const float* __restrict__ gbuf,
    float* __restrict__ cell, unsigned short* __restrict__ hbf, const float* __restrict__ W,
    const float* __restrict__ b, float* __restrict__ y, int t){
  __shared__ float h[256];
  int tid = threadIdx.x;
  int r = tid >> 7, o = tid & 127;
  int n = blockIdx.x*2 + r;
  size_t idx = (size_t)n*128 + o;
  float g0 = gbuf[idx], g1 = gbuf[262144+idx], g2 = gbuf[524288+idx], g3 = gbuf[786432+idx];
  float fg = sigm(g0), ig = sigm(g1), ic = tanhf(g2), og = sigm(g3);
  float cl = cell[idx]*fg + ig*ic;
  float hd = tanhf(cl)*og;
  cell[idx] = cl; hbf[idx] = f2bf(hd);
  h[tid] = hd;
  __syncthreads();
  float acc = b[o];
  const float* hr = h + r*128;
  for (int k=0;k<128;++k) acc += hr[k]*W[k*128+o];
  y[(size_t)n*512 + o*4 + t] = sigm(acc);
}

// ---- temporal conv layers (transposed weights: coalesced) ----
template<int TIN, bool LAST>
__global__ __launch_bounds__(256) void conv_kernel(const float* __restrict__ yin,
    const float* __restrict__ cwT, const float* __restrict__ cb, float* __restrict__ yout, int l){
  __shared__ float ylds[2][128][4];
  int tid = threadIdx.x;
  int r = tid >> 7, o = tid & 127;
  int n = blockIdx.x*2 + r;
  float4 yv = *(const float4*)&yin[(size_t)n*512 + o*4];
  *(float4*)&ylds[r][o][0] = yv;
  __syncthreads();
  const float* w = cwT + (size_t)l*32768;
  float acc[TIN-1];
  #pragma unroll
  for (int j=0;j<TIN-1;++j) acc[j] = 0.f;
  for (int k=0;k<128;++k){
    float w0 = w[k*256 + o], w1 = w[k*256 + 128 + o];
    float y0 = ylds[r][k][0], y1 = ylds[r][k][1];
    acc[0] += y0*w0 + y1*w1;
    if (TIN > 2){
      float y2 = ylds[r][k][2];
      acc[1] += y1*w0 + y2*w1;
      if (TIN > 3){
        float y3 = ylds[r][k][3];
        acc[2] += y2*w0 + y3*w1;
      }
    }
  }
  float bb = cb[l*128 + o];
  if (LAST){
    yout[(size_t)n*128 + o] = acc[0] + bb;
  } else {
    #pragma unroll
    for (int tt=0; tt<TIN-1; ++tt) yout[(size_t)n*512 + o*4 + tt] = acc[tt] + bb;
  }
}

extern "C" void kernel_launch(void* const* d_in, const int* in_sizes, int n_in,
                              void* d_out, int out_size, void* d_ws, size_t ws_size,
                              hipStream_t stream) {
  const float* actors = (const float*)d_in[0];
  const int*   adj    = (const int*)d_in[1];
  const float* Wg     = (const float*)d_in[2];
  const float* ag     = (const float*)d_in[3];
  const float* W      = (const float*)d_in[4];
  const float* b      = (const float*)d_in[5];
  const float* h0     = (const float*)d_in[6];
  const float* cw     = (const float*)d_in[7];
  const float* cb     = (const float*)d_in[8];
  float* out = (float*)d_out;

  char* ws = (char*)d_ws;
  unsigned long long* bm = (unsigned long long*)ws;                  // 2 MB
  float* cell          = (float*)(ws + (size_t)(2u<<20));            // 1 MB
  unsigned short* hbf  = (unsigned short*)(ws + (size_t)(3u<<20));   // 512 KB bf16 [n][k]
  unsigned short* WgT  = (unsigned short*)(ws + (size_t)3670016);    // 256 KB bf16 [g][o][f]
  float* s_src         = (float*)(ws + (size_t)3932160);             // 32 KB
  float* s_dst         = (float*)(ws + (size_t)3932160 + 32768);     // 32 KB
  unsigned short* WhT  = (unsigned short*)(ws + (size_t)(4u<<20));   // 2 MB bf16 [g][o][n]
  float* cwT           = (float*)(ws + (size_t)(6u<<20));            // 384 KB [l][k][tap][o]
  float* gbuf          = (float*)(ws + (size_t)(7u<<20));            // 4 MB [g][n][o]
  float* yA            = (float*)(ws + (size_t)(11u<<20));           // 4 MB [n][o][4]
  float* yB            = (float*)(ws + (size_t)(15u<<20));           // 4 MB

  const int XI[4] = {4, 9, 14, 19};

  init_kernel<<<1024, 256, 0, stream>>>(actors, h0, hbf, cell);
  wgt_kernel<<<512, 256, 0, stream>>>(Wg, WgT);
  cwt_kernel<<<192, 256, 0, stream>>>(cw, cwT);
  mask_kernel<<<dim3(512,4), 256, 0, stream>>>(adj, bm);
  for (int t=0; t<4; ++t){
    whgemm_kernel<<<dim3(64,4), 256, 0, stream>>>(actors, hbf, WgT, ag, WhT, s_src, s_dst, XI[t]*128);
    attn_kernel  <<<dim3(64,4), 512, 0, stream>>>(bm, WhT, s_src, s_dst, gbuf, t);
    gate_kernel  <<<1024, 256, 0, stream>>>(gbuf, cell, hbf, W, b, yA, t);
  }
  conv_kernel<4,false><<<1024, 256, 0, stream>>>(yA, cwT, cb, yB, 0);
  conv_kernel<3,false><<<1024, 256, 0, stream>>>(yB, cwT, cb, yA, 1);
  conv_kernel<2,true> <<<1024, 256, 0, stream>>>(yA, cwT, cb, out, 2);
}